// Round 1
// baseline (126.105 us; speedup 1.0000x reference)
//
#include <hip/hip_runtime.h>

// CostVolume via banded-correlation MFMA (v_mfma_f32_16x16x32_f16), 3-pass.
// cost[b,h,w,(sh+4)*9+(sw+4)] = LeakyReLU_0.1( mean_c x1[b,h,w,c]*warped[b,h+sh,w+sw,c] )
// B=8 H=128 W=192 C=128, MD=4. Output fp32 [B,H,W,81].
//
// Block = 8 h-rows x 16 w-px, 8 waves (wave = one h-row).
// The 9 sh values are split into 3 passes of 3 (NSH=3): per pass the block
// stages only 10 warped rows and the wave keeps 3*2=6 f32x4 accumulators
// (24 regs) instead of 18 (72) -> combined VGPR+AGPR ~<=80 -> 6-8 waves/SIMD
// (was ~3-4: 64 arch + 72 acc = 136). K completes within a pass, so the
// 27-float sh-slice (k-dim is sh-major) is stored per pass and acc reused.
// Raw `s_waitcnt lgkmcnt(0); s_barrier` instead of __syncthreads so prefetch
// global loads are NOT drained at barriers (all cross-wave comms are LDS).
// LDS = 2*15360 (dbuf staging) + 6912 (half-rows epilogue) = 36.75 KiB.

namespace {
constexpr int Bb = 8, Hh = 128, Ww = 192, Cn = 128;
constexpr int MDc = 4;
constexpr int TH = 8, TWT = 16;        // block tile: 8 rows x 16 px
constexpr int NTHR = 512;              // 8 waves
constexpr int NSH = 3;                 // sh per pass
constexpr int NPASS = 3;               // 3*3 = 9 sh total
constexpr int RH = TH + NSH - 1;       // 10 staged warped rows per pass
constexpr int RPX = 24;                // staged warped px (w0-4 .. w0+19)
constexpr int KC = 32;                 // channels per chunk
constexpr int NCH = Cn / KC;           // 4
constexpr int NSTEP = NPASS * NCH;     // 12 pipeline steps
constexpr int KQB = RPX * 16;          // 384 B per kq-plane
constexpr int ROWB = 4 * KQB;          // 1536 B per staged row
constexpr int BUFB = RH * ROWB;        // 15360 B per buffer
constexpr int RUNS = RH * RPX * 4;     // 960 8-channel runs per chunk
constexpr int NIT = 2;                 // ceil(960/512); it=1 active for tid<448
constexpr int EPIROWS = 4;             // epilogue row-group size
constexpr int EPIF = TWT * NSH * 9;    // 432 floats per row per pass
constexpr int EPIB = EPIROWS * EPIF * 4;   // 6912 B
constexpr float NEG = 0.1f;
}

typedef __fp16 h2v   __attribute__((ext_vector_type(2)));
typedef __fp16 f16x8 __attribute__((ext_vector_type(8)));
typedef float  f32x4 __attribute__((ext_vector_type(4)));

__device__ __forceinline__ unsigned pkh2(float a, float b) {
    h2v h = __builtin_amdgcn_cvt_pkrtz(a, b);
    return __builtin_bit_cast(unsigned, h);
}

// Barrier with LDS-only drain: global prefetch loads stay in flight across it.
__device__ __forceinline__ void barrier_lgkm() {
    asm volatile("s_waitcnt lgkmcnt(0)\n\ts_barrier" ::: "memory");
}

__global__ __launch_bounds__(NTHR, 6)
void costvol_mfma(const float* __restrict__ x1,
                  const float* __restrict__ wp,
                  float* __restrict__ out)
{
    __shared__ __align__(16) unsigned char smem[2 * BUFB + EPIB];   // 37632 B

    const int tid  = threadIdx.x;
    const int wv   = tid >> 6;        // 0..7 : h-row within stripe
    const int lane = tid & 63;
    const int nI   = lane & 15;       // A-row m / B-col n lane index
    const int kq   = lane >> 4;       // 0..3 : k-group (8 channels each)

    const int w0 = blockIdx.x * TWT;
    const int h0 = blockIdx.y * TH;
    const int b  = blockIdx.z;

    // ---- A fragments in registers: x1[h0+wv, w0+nI, ch*32 + kq*8 .. +7] ----
    uint4 afr[NCH];
    {
        const float* xp = x1 + ((size_t)((b * Hh + h0 + wv) * Ww) + w0 + nI) * Cn + kq * 8;
#pragma unroll
        for (int ch = 0; ch < NCH; ++ch) {
            float4 u = *reinterpret_cast<const float4*>(xp + ch * KC);
            float4 v = *reinterpret_cast<const float4*>(xp + ch * KC + 4);
            afr[ch] = make_uint4(pkh2(u.x, u.y), pkh2(u.z, u.w),
                                 pkh2(v.x, v.y), pkh2(v.z, v.w));
        }
    }

    // ---- staging decode: run = (row, px, kq), kq innermost; pass-invariant l_off ----
    int l_off[NIT];
#pragma unroll
    for (int it = 0; it < NIT; ++it) {
        int s   = tid + it * NTHR;
        int skq = s & 3;
        int t   = s >> 2;
        int px  = t % RPX;
        int row = t / RPX;
        l_off[it] = row * ROWB + skq * KQB + ((px ^ (skq << 1)) * 16);
    }

    int g_off[NIT]; bool g_ok[NIT];
    auto OFFS = [&](int pass) {
#pragma unroll
        for (int it = 0; it < NIT; ++it) {
            int s   = tid + it * NTHR;
            int skq = s & 3;
            int t   = s >> 2;
            int px  = t % RPX;
            int row = t / RPX;
            int hw  = h0 - MDc + pass * NSH + row;
            int ww  = w0 - MDc + px;
            bool ok = (s < RUNS) && (unsigned)hw < (unsigned)Hh && (unsigned)ww < (unsigned)Ww;
            g_ok[it]  = ok;
            g_off[it] = ((b * Hh + (ok ? hw : 0)) * Ww + (ok ? ww : 0)) * Cn + skq * 8;
        }
    };

    uint4 gp[NIT];
    auto LOADCH = [&](int ch) {
#pragma unroll
        for (int it = 0; it < NIT; ++it) {
            if (g_ok[it]) {
                const float* p = wp + g_off[it] + ch * KC;
                float4 u = *reinterpret_cast<const float4*>(p);
                float4 v = *reinterpret_cast<const float4*>(p + 4);
                gp[it] = make_uint4(pkh2(u.x, u.y), pkh2(u.z, u.w),
                                    pkh2(v.x, v.y), pkh2(v.z, v.w));
            } else {
                gp[it] = make_uint4(0u, 0u, 0u, 0u);
            }
        }
    };
    auto WRITEB = [&](int buf) {
        *reinterpret_cast<uint4*>(smem + buf * BUFB + l_off[0]) = gp[0];
        if (tid < RUNS - NTHR)   // it=1 run exists only for tid<448
            *reinterpret_cast<uint4*>(smem + buf * BUFB + l_off[1]) = gp[1];
    };

    f32x4 ac0[NSH], ac1[NSH];
    auto ZEROACC = [&]() {
#pragma unroll
        for (int s = 0; s < NSH; ++s) {
            f32x4 z = {0.f, 0.f, 0.f, 0.f};
            ac0[s] = z; ac1[s] = z;
        }
    };
    ZEROACC();

    // per-lane B fragment offsets within a staged row (conflict-free)
    const int ro0 = kq * KQB + ((nI       ^ (kq << 1)) * 16);
    const int ro1 = kq * KQB + (((nI + 8) ^ (kq << 1)) * 16);

    float* epi = reinterpret_cast<float*>(smem + 2 * BUFB);
    const float sc = 1.0f / (float)Cn;

    // band extraction for this wave's row into epi[wv-rowbase]
    // C/D map: col=n=lane&15, row=m=(lane>>4)*4+reg
    // tile0: j-sw = n-m in [0,8]; tile1: j-sw = n-m+8, valid n-m in [-8,0] && n>=8
    auto BANDS = [&](int rowbase) {
        float* rowp = epi + (wv - rowbase) * EPIF;
#pragma unroll
        for (int rg = 0; rg < 4; ++rg) {
            int m = kq * 4 + rg;
            int d = nI - m;
            if (d >= 0 && d <= 8) {
#pragma unroll
                for (int s = 0; s < NSH; ++s) {
                    float v = ac0[s][rg] * sc;
                    v = (v >= 0.f) ? v : NEG * v;
                    rowp[m * 27 + s * 9 + d] = v;
                }
            }
            if (d >= -8 && d <= 0 && nI >= 8) {
#pragma unroll
                for (int s = 0; s < NSH; ++s) {
                    float v = ac1[s][rg] * sc;
                    v = (v >= 0.f) ? v : NEG * v;
                    rowp[m * 27 + s * 9 + d + 8] = v;
                }
            }
        }
    };
    // cooperative store of EPIROWS rows x 432 floats; k-slice = pass*27..+27
    auto STORE4 = [&](int pass, int rowbase) {
        for (int q = tid; q < EPIROWS * EPIF; q += NTHR) {
            int row = q / EPIF;
            int rem = q - row * EPIF;
            int px  = rem / 27;
            int j   = rem - px * 27;
            size_t go = ((size_t)((b * Hh + h0 + rowbase + row) * Ww + w0 + px)) * 81
                        + pass * 27 + j;
            out[go] = epi[q];
        }
    };

    OFFS(0);
    LOADCH(0); WRITEB(0); LOADCH(1);

    int cur = 0;
#pragma unroll
    for (int t = 0; t < NSTEP; ++t) {
        barrier_lgkm();                           // buf[t&1] visible; prior readers done
        if (t + 1 < NSTEP) WRITEB(cur ^ 1);       // gp holds step t+1 data
        if (t + 2 < NSTEP) {
            int nt = t + 2;
            if ((nt & (NCH - 1)) == 0) OFFS(nt >> 2);   // pass boundary for prefetch
            LOADCH(nt & (NCH - 1));
        }
        f16x8 av = __builtin_bit_cast(f16x8, afr[t & (NCH - 1)]);
        const unsigned char* base = smem + cur * BUFB;
#pragma unroll
        for (int s = 0; s < NSH; ++s) {
            const unsigned char* rp = base + (wv + s) * ROWB;   // staged row wv+s
            uint4 b0 = *reinterpret_cast<const uint4*>(rp + ro0);
            uint4 b1 = *reinterpret_cast<const uint4*>(rp + ro1);
            ac0[s] = __builtin_amdgcn_mfma_f32_16x16x32_f16(
                av, __builtin_bit_cast(f16x8, b0), ac0[s], 0, 0, 0);
            ac1[s] = __builtin_amdgcn_mfma_f32_16x16x32_f16(
                av, __builtin_bit_cast(f16x8, b1), ac1[s], 0, 0, 0);
        }
        cur ^= 1;

        if ((t & (NCH - 1)) == NCH - 1) {         // K complete for this pass
            int pass = t >> 2;
            if (wv < 4) BANDS(0);
            barrier_lgkm();
            STORE4(pass, 0);
            barrier_lgkm();
            if (wv >= 4) BANDS(4);
            barrier_lgkm();
            STORE4(pass, 4);
            ZEROACC();                            // acc reused next pass
            // epi WAR vs next pass covered by the 4 step-barriers in between
        }
    }
}

extern "C" void kernel_launch(void* const* d_in, const int* in_sizes, int n_in,
                              void* d_out, int out_size, void* d_ws, size_t ws_size,
                              hipStream_t stream) {
    const float* x1 = (const float*)d_in[0];
    const float* wp = (const float*)d_in[1];
    float* out = (float*)d_out;
    dim3 grid(Ww / TWT, Hh / TH, Bb);   // 12 x 16 x 8 = 1536 blocks
    costvol_mfma<<<grid, NTHR, 0, stream>>>(x1, wp, out);
}

// Round 2
// 86.967 us; speedup vs baseline: 1.4500x; 1.4500x over previous
//
#include <hip/hip_runtime.h>

// CostVolume via banded-correlation MFMA (v_mfma_f32_16x16x32_f16).
// cost[b,h,w,(sh+4)*9+(sw+4)] = LeakyReLU_0.1( mean_c x1[b,h,w,c]*warped[b,h+sh,w+sw,c] )
// B=8 H=128 W=192 C=128, MD=4. Output fp32 [B,H,W,81].
//
// Round-0 structure (best: 87.2 us) with ONE change: all __syncthreads()
// replaced by raw `s_waitcnt lgkmcnt(0); s_barrier`. hipcc's __syncthreads
// emits s_waitcnt vmcnt(0) before s_barrier, draining the prefetch global
// loads at every K-step barrier — the depth-2 prefetch never spanned a
// barrier and ~900cy HBM latency was re-exposed 4x per block. All
// cross-wave communication here is via LDS (lgkm-drained); global loads
// land in registers (gp) whose use is compiler-vmcnt-tracked. So the
// lgkm-only barrier is safe and lets loads stay in flight across steps.
//
// Block = 8 h-rows x 16 w-px, 8 waves (wave = one h-row, all 81 shifts).
// Per (wave, sh): C[i,j] = sum_c A[i,c] * Bt[j,c] over staged warped px;
//   two B tiles at staged offsets 0 (+8): tile0 covers m+sw4<=15, tile1 >=16.
// A (x1) kept in REGISTERS (coalesced 16px x 32ch wave loads, no LDS).
// Warped staged in LDS as [row][kq][n ^ (kq<<1)] 16B slots: conflict-free for
// both staging b128 writes and B-fragment b128 reads (octet quads distinct).
// K-chunks of 32 channels, double-buffered, depth-2 register prefetch.
// Epilogue: band extraction -> LDS -> coalesced float4 stores.

namespace {
constexpr int Bb = 8, Hh = 128, Ww = 192, Cn = 128;
constexpr int MDc = 4;
constexpr int TH = 8, TWT = 16;        // block tile: 8 rows x 16 px
constexpr int NTHR = 512;              // 8 waves
constexpr int RH = 16;                 // staged warped rows  (h0-4 .. h0+11)
constexpr int RPX = 24;                // staged warped px    (w0-4 .. w0+19)
constexpr int KC = 32;                 // channels per chunk
constexpr int NCH = Cn / KC;           // 4
constexpr int KQB = RPX * 16;          // 384 B per kq-plane (24 x 16B slots)
constexpr int ROWB = 4 * KQB;          // 1536 B per staged row
constexpr int BUFB = RH * ROWB;        // 24576 B per buffer
constexpr int RUNS = RH * RPX * 4;     // 1536 8-channel runs per chunk
constexpr int NIT = RUNS / NTHR;       // 3
constexpr float NEG = 0.1f;
}

typedef __fp16 h2v   __attribute__((ext_vector_type(2)));
typedef __fp16 f16x8 __attribute__((ext_vector_type(8)));
typedef float  f32x4 __attribute__((ext_vector_type(4)));

__device__ __forceinline__ unsigned pkh2(float a, float b) {
    h2v h = __builtin_amdgcn_cvt_pkrtz(a, b);
    return __builtin_bit_cast(unsigned, h);
}

// Barrier with LDS-only drain: global prefetch loads stay in flight across it.
__device__ __forceinline__ void barrier_lgkm() {
    asm volatile("s_waitcnt lgkmcnt(0)\n\ts_barrier" ::: "memory");
}

__global__ __launch_bounds__(NTHR, 4)
void costvol_mfma(const float* __restrict__ x1,
                  const float* __restrict__ wp,
                  float* __restrict__ out)
{
    __shared__ __align__(16) unsigned char smem[2 * BUFB];   // 48 KiB

    const int tid  = threadIdx.x;
    const int wv   = tid >> 6;        // 0..7 : h-row within stripe
    const int lane = tid & 63;
    const int nI   = lane & 15;       // A-row m / B-col n lane index
    const int kq   = lane >> 4;       // 0..3 : k-group (8 channels each)

    const int w0 = blockIdx.x * TWT;
    const int h0 = blockIdx.y * TH;
    const int b  = blockIdx.z;

    // ---- A fragments in registers: x1[h0+wv, w0+nI, ch*32 + kq*8 .. +7] ----
    uint4 afr[NCH];
    {
        const float* xp = x1 + ((size_t)((b * Hh + h0 + wv) * Ww) + w0 + nI) * Cn + kq * 8;
#pragma unroll
        for (int ch = 0; ch < NCH; ++ch) {
            float4 u = *reinterpret_cast<const float4*>(xp + ch * KC);
            float4 v = *reinterpret_cast<const float4*>(xp + ch * KC + 4);
            afr[ch] = make_uint4(pkh2(u.x, u.y), pkh2(u.z, u.w),
                                 pkh2(v.x, v.y), pkh2(v.z, v.w));
        }
    }

    // ---- warped staging decode: run = (row, px, kq), kq innermost ----
    int g_off[NIT]; int l_off[NIT]; bool g_ok[NIT];
#pragma unroll
    for (int it = 0; it < NIT; ++it) {
        int s   = tid + it * NTHR;    // 0..1535
        int skq = s & 3;
        int t   = s >> 2;             // 0..383
        int px  = t % RPX;
        int row = t / RPX;
        int hw  = h0 - MDc + row;
        int ww  = w0 - MDc + px;
        bool ok = (unsigned)hw < (unsigned)Hh && (unsigned)ww < (unsigned)Ww;
        g_ok[it]  = ok;
        g_off[it] = ((b * Hh + (ok ? hw : 0)) * Ww + (ok ? ww : 0)) * Cn + skq * 8;
        l_off[it] = row * ROWB + skq * KQB + ((px ^ (skq << 1)) * 16);
    }

    uint4 gp[NIT];
    auto LOADCH = [&](int ch) {
#pragma unroll
        for (int it = 0; it < NIT; ++it) {
            if (g_ok[it]) {
                const float* p = wp + g_off[it] + ch * KC;
                float4 u = *reinterpret_cast<const float4*>(p);
                float4 v = *reinterpret_cast<const float4*>(p + 4);
                gp[it] = make_uint4(pkh2(u.x, u.y), pkh2(u.z, u.w),
                                    pkh2(v.x, v.y), pkh2(v.z, v.w));
            } else {
                gp[it] = make_uint4(0u, 0u, 0u, 0u);
            }
        }
    };
    auto WRITEB = [&](int buf) {
#pragma unroll
        for (int it = 0; it < NIT; ++it)
            *reinterpret_cast<uint4*>(smem + buf * BUFB + l_off[it]) = gp[it];
    };

    f32x4 ac0[9], ac1[9];
#pragma unroll
    for (int s = 0; s < 9; ++s) {
        f32x4 z = {0.f, 0.f, 0.f, 0.f};
        ac0[s] = z; ac1[s] = z;
    }

    // per-lane B fragment offsets within a staged row (both conflict-free)
    const int ro0 = kq * KQB + ((nI       ^ (kq << 1)) * 16);
    const int ro1 = kq * KQB + (((nI + 8) ^ (kq << 1)) * 16);

    LOADCH(0); WRITEB(0); LOADCH(1);

    int cur = 0;
#pragma unroll
    for (int ch = 0; ch < NCH; ++ch) {
        barrier_lgkm();
        if (ch + 1 < NCH) WRITEB(cur ^ 1);
        if (ch + 2 < NCH) LOADCH(ch + 2);
        f16x8 av = __builtin_bit_cast(f16x8, afr[ch]);
        const unsigned char* base = smem + cur * BUFB;
#pragma unroll
        for (int sh = 0; sh < 9; ++sh) {
            const unsigned char* rp = base + (wv + sh) * ROWB;   // staged row ly+sh
            uint4 b0 = *reinterpret_cast<const uint4*>(rp + ro0);
            uint4 b1 = *reinterpret_cast<const uint4*>(rp + ro1);
            ac0[sh] = __builtin_amdgcn_mfma_f32_16x16x32_f16(
                av, __builtin_bit_cast(f16x8, b0), ac0[sh], 0, 0, 0);
            ac1[sh] = __builtin_amdgcn_mfma_f32_16x16x32_f16(
                av, __builtin_bit_cast(f16x8, b1), ac1[sh], 0, 0, 0);
        }
        cur ^= 1;
    }

    barrier_lgkm();   // all B reads done; reuse smem for epilogue

    // ---- band extraction: C/D map col=n=lane&15, row=m=(lane>>4)*4+reg ----
    // tile0: sw4 = n-m in [0,8]  (covers m+sw4 <= 15)
    // tile1: sw4 = n-m+8, valid when n-m in [-8,0] && n>=8 (covers m+sw4 >= 16)
    float* outb = reinterpret_cast<float*>(smem);   // [8][16*81] = 41472 B
    const float sc = 1.0f / (float)Cn;
#pragma unroll
    for (int rg = 0; rg < 4; ++rg) {
        int m = kq * 4 + rg;
        int d = nI - m;
        if (d >= 0 && d <= 8) {
#pragma unroll
            for (int sh = 0; sh < 9; ++sh) {
                float v = ac0[sh][rg] * sc;
                v = (v >= 0.f) ? v : NEG * v;
                outb[wv * (TWT * 81) + m * 81 + sh * 9 + d] = v;
            }
        }
        if (d >= -8 && d <= 0 && nI >= 8) {
#pragma unroll
            for (int sh = 0; sh < 9; ++sh) {
                float v = ac1[sh][rg] * sc;
                v = (v >= 0.f) ? v : NEG * v;
                outb[wv * (TWT * 81) + m * 81 + sh * 9 + d + 8] = v;
            }
        }
    }
    barrier_lgkm();

    // ---- cooperative coalesced store: 8 rows x 1296 contiguous floats ----
    constexpr int ROWF4 = TWT * 81 / 4;          // 324 float4 per row
    for (int q = tid; q < TH * ROWF4; q += NTHR) {
        float4 v = *reinterpret_cast<const float4*>(outb + q * 4);
        int row = q / ROWF4;
        int rem = q - row * ROWF4;
        size_t bo = ((size_t)((b * Hh + h0 + row) * Ww + w0)) * 81 + (size_t)rem * 4;
        *reinterpret_cast<float4*>(out + bo) = v;
    }
}

extern "C" void kernel_launch(void* const* d_in, const int* in_sizes, int n_in,
                              void* d_out, int out_size, void* d_ws, size_t ws_size,
                              hipStream_t stream) {
    const float* x1 = (const float*)d_in[0];
    const float* wp = (const float*)d_in[1];
    float* out = (float*)d_out;
    dim3 grid(Ww / TWT, Hh / TH, Bb);   // 12 x 16 x 8 = 1536 blocks
    costvol_mfma<<<grid, NTHR, 0, stream>>>(x1, wp, out);
}

// Round 3
// 77.885 us; speedup vs baseline: 1.6191x; 1.1166x over previous
//
#include <hip/hip_runtime.h>

// CostVolume via banded-correlation MFMA (v_mfma_f32_16x16x32_f16).
// cost[b,h,w,(sh+4)*9+(sw+4)] = LeakyReLU_0.1( mean_c x1[b,h,w,c]*warped[b,h+sh,w+sw,c] )
// B=8 H=128 W=192 C=128, MD=4. Output fp32 [B,H,W,81].
//
// Round-3 changes vs the 87.1us baseline (theory: phase-chain too long, HBM
// idles ~55% because only ~2 resident blocks alternate mem-wait/compute):
//  1. DIRECT scattered global stores replace the LDS epilogue round-trip.
//     Old epilogue: band->LDS (provable 4-way kq bank conflict: bank =
//     (kq*320+...)%32, 320%32==0) -> barrier -> 41.5KB LDS->reg->global.
//     New: each lane stores its band values straight to out; per (rg,sh,tile)
//     the 9 active lanes per kq-quad write 36B contiguous runs that L2
//     merges. Removes 2 barriers + ~3.7K conflict cy/block + a whole
//     HBM-idle phase.
//  2. XCD-aware swizzle: 1536 blocks = 8 XCDs x 192, and 192 = one full
//     batch image (12x16 tiles) -> each XCD gets one image; all halo-sharing
//     neighbor tiles hit the same L2.
//  3. Warped staging loads issued before x1 fragment loads in the prologue.
//
// Block = 8 h-rows x 16 w-px, 8 waves (wave = one h-row, all 81 shifts).
// Per (wave, sh): C[i,j] = sum_c A[i,c] * Bt[j,c] over staged warped px;
//   two B tiles at staged offsets 0 (+8): tile0 covers m+sw4<=15, tile1 >=16.
// A (x1) kept in REGISTERS. Warped staged in LDS as [row][kq][px ^ (kq<<1)]
// 16B slots (conflict-free staging writes and B-fragment reads).
// K-chunks of 32 channels, double-buffered, depth-2 register prefetch.

namespace {
constexpr int Bb = 8, Hh = 128, Ww = 192, Cn = 128;
constexpr int MDc = 4;
constexpr int TH = 8, TWT = 16;        // block tile: 8 rows x 16 px
constexpr int NTHR = 512;              // 8 waves
constexpr int RH = 16;                 // staged warped rows  (h0-4 .. h0+11)
constexpr int RPX = 24;                // staged warped px    (w0-4 .. w0+19)
constexpr int KC = 32;                 // channels per chunk
constexpr int NCH = Cn / KC;           // 4
constexpr int KQB = RPX * 16;          // 384 B per kq-plane (24 x 16B slots)
constexpr int ROWB = 4 * KQB;          // 1536 B per staged row
constexpr int BUFB = RH * ROWB;        // 24576 B per buffer
constexpr int RUNS = RH * RPX * 4;     // 1536 8-channel runs per chunk
constexpr int NIT = RUNS / NTHR;       // 3
constexpr float NEG = 0.1f;
}

typedef __fp16 h2v   __attribute__((ext_vector_type(2)));
typedef __fp16 f16x8 __attribute__((ext_vector_type(8)));
typedef float  f32x4 __attribute__((ext_vector_type(4)));

__device__ __forceinline__ unsigned pkh2(float a, float b) {
    h2v h = __builtin_amdgcn_cvt_pkrtz(a, b);
    return __builtin_bit_cast(unsigned, h);
}

// Barrier with LDS-only drain: global prefetch loads stay in flight across it.
__device__ __forceinline__ void barrier_lgkm() {
    asm volatile("s_waitcnt lgkmcnt(0)\n\ts_barrier" ::: "memory");
}

__global__ __launch_bounds__(NTHR, 4)
void costvol_mfma(const float* __restrict__ x1,
                  const float* __restrict__ wp,
                  float* __restrict__ out)
{
    __shared__ __align__(16) unsigned char smem[2 * BUFB];   // 48 KiB

    const int tid  = threadIdx.x;
    const int wv   = tid >> 6;        // 0..7 : h-row within stripe
    const int lane = tid & 63;
    const int nI   = lane & 15;       // A-row m / B-col n lane index
    const int kq   = lane >> 4;       // 0..3 : k-group (8 channels each)

    // XCD swizzle: linear id round-robins across 8 XCDs; remap so XCD x gets
    // 192 consecutive wg = one full batch image (12 x 16 tiles).
    const int id = blockIdx.x;
    const int wg = (id & 7) * 192 + (id >> 3);
    const int bx = wg % 12;
    const int t2 = wg / 12;
    const int by = t2 & 15;
    const int bz = t2 >> 4;

    const int w0 = bx * TWT;
    const int h0 = by * TH;
    const int b  = bz;

    // ---- warped staging decode: run = (row, px, kq), kq innermost ----
    int g_off[NIT]; int l_off[NIT]; bool g_ok[NIT];
#pragma unroll
    for (int it = 0; it < NIT; ++it) {
        int s   = tid + it * NTHR;    // 0..1535
        int skq = s & 3;
        int t   = s >> 2;             // 0..383
        int px  = t % RPX;
        int row = t / RPX;
        int hw  = h0 - MDc + row;
        int ww  = w0 - MDc + px;
        bool ok = (unsigned)hw < (unsigned)Hh && (unsigned)ww < (unsigned)Ww;
        g_ok[it]  = ok;
        g_off[it] = ((b * Hh + (ok ? hw : 0)) * Ww + (ok ? ww : 0)) * Cn + skq * 8;
        l_off[it] = row * ROWB + skq * KQB + ((px ^ (skq << 1)) * 16);
    }

    uint4 gp[NIT];
    auto LOADCH = [&](int ch) {
#pragma unroll
        for (int it = 0; it < NIT; ++it) {
            if (g_ok[it]) {
                const float* p = wp + g_off[it] + ch * KC;
                float4 u = *reinterpret_cast<const float4*>(p);
                float4 v = *reinterpret_cast<const float4*>(p + 4);
                gp[it] = make_uint4(pkh2(u.x, u.y), pkh2(u.z, u.w),
                                    pkh2(v.x, v.y), pkh2(v.z, v.w));
            } else {
                gp[it] = make_uint4(0u, 0u, 0u, 0u);
            }
        }
    };
    auto WRITEB = [&](int buf) {
#pragma unroll
        for (int it = 0; it < NIT; ++it)
            *reinterpret_cast<uint4*>(smem + buf * BUFB + l_off[it]) = gp[it];
    };

    // issue first staging chunk before x1 loads (staging is the critical path)
    LOADCH(0);

    // ---- A fragments in registers: x1[h0+wv, w0+nI, ch*32 + kq*8 .. +7] ----
    uint4 afr[NCH];
    {
        const float* xp = x1 + ((size_t)((b * Hh + h0 + wv) * Ww) + w0 + nI) * Cn + kq * 8;
#pragma unroll
        for (int ch = 0; ch < NCH; ++ch) {
            float4 u = *reinterpret_cast<const float4*>(xp + ch * KC);
            float4 v = *reinterpret_cast<const float4*>(xp + ch * KC + 4);
            afr[ch] = make_uint4(pkh2(u.x, u.y), pkh2(u.z, u.w),
                                 pkh2(v.x, v.y), pkh2(v.z, v.w));
        }
    }

    f32x4 ac0[9], ac1[9];
#pragma unroll
    for (int s = 0; s < 9; ++s) {
        f32x4 z = {0.f, 0.f, 0.f, 0.f};
        ac0[s] = z; ac1[s] = z;
    }

    // per-lane B fragment offsets within a staged row (both conflict-free)
    const int ro0 = kq * KQB + ((nI       ^ (kq << 1)) * 16);
    const int ro1 = kq * KQB + (((nI + 8) ^ (kq << 1)) * 16);

    WRITEB(0); LOADCH(1);

    int cur = 0;
#pragma unroll
    for (int ch = 0; ch < NCH; ++ch) {
        barrier_lgkm();
        if (ch + 1 < NCH) WRITEB(cur ^ 1);
        if (ch + 2 < NCH) LOADCH(ch + 2);
        f16x8 av = __builtin_bit_cast(f16x8, afr[ch]);
        const unsigned char* base = smem + cur * BUFB;
#pragma unroll
        for (int sh = 0; sh < 9; ++sh) {
            const unsigned char* rp = base + (wv + sh) * ROWB;   // staged row ly+sh
            uint4 b0 = *reinterpret_cast<const uint4*>(rp + ro0);
            uint4 b1 = *reinterpret_cast<const uint4*>(rp + ro1);
            ac0[sh] = __builtin_amdgcn_mfma_f32_16x16x32_f16(
                av, __builtin_bit_cast(f16x8, b0), ac0[sh], 0, 0, 0);
            ac1[sh] = __builtin_amdgcn_mfma_f32_16x16x32_f16(
                av, __builtin_bit_cast(f16x8, b1), ac1[sh], 0, 0, 0);
        }
        cur ^= 1;
    }

    // ---- direct band stores: no LDS round-trip, no barriers ----
    // C/D map: col=n=lane&15, row=m=(lane>>4)*4+reg
    // tile0: staged px p = nI      -> (m, sw4 = nI-m),   valid d=nI-m in [0,8]
    // tile1: staged px p = nI + 8  -> (m, sw4 = nI-m+8), valid d in [-8,0] && nI>=8
    // out k-index = sh*9 + sw4. Active lanes per (rg,sh,tile) write 4
    // contiguous 36B runs (one per kq) -> merged to full lines in L2.
    const float sc = 1.0f / (float)Cn;
    const size_t rowbase = ((size_t)((b * Hh + h0 + wv) * Ww) + w0) * 81;
#pragma unroll
    for (int rg = 0; rg < 4; ++rg) {
        int m = kq * 4 + rg;
        int d = nI - m;
        bool t0 = (d >= 0 && d <= 8);
        bool t1 = (d >= -8 && d <= 0 && nI >= 8);
        size_t mb = rowbase + (size_t)m * 81;
#pragma unroll
        for (int sh = 0; sh < 9; ++sh) {
            if (t0) {
                float v = ac0[sh][rg] * sc;
                v = (v >= 0.f) ? v : NEG * v;
                out[mb + sh * 9 + d] = v;
            }
            if (t1) {
                float v = ac1[sh][rg] * sc;
                v = (v >= 0.f) ? v : NEG * v;
                out[mb + sh * 9 + d + 8] = v;
            }
        }
    }
}

extern "C" void kernel_launch(void* const* d_in, const int* in_sizes, int n_in,
                              void* d_out, int out_size, void* d_ws, size_t ws_size,
                              hipStream_t stream) {
    const float* x1 = (const float*)d_in[0];
    const float* wp = (const float*)d_in[1];
    float* out = (float*)d_out;
    dim3 grid(12 * 16 * 8, 1, 1);   // 1536 blocks, XCD-swizzled in-kernel
    costvol_mfma<<<grid, NTHR, 0, stream>>>(x1, wp, out);
}

// Round 4
// 59.654 us; speedup vs baseline: 2.1139x; 1.3056x over previous
//
#include <hip/hip_runtime.h>

// CostVolume via banded-correlation MFMA (v_mfma_f32_16x16x32_f16).
// cost[b,h,w,(sh+4)*9+(sw+4)] = LeakyReLU_0.1( mean_c x1[b,h,w,c]*warped[b,h+sh,w+sw,c] )
// B=8 H=128 W=192 C=128, MD=4. Output fp32 [B,H,W,81].
//
// Round-4 change vs 77.9us round-3: cut arch VGPRs 64 -> ~56 so combined
// VGPR+AGPR (56 + 72 acc = 128) fits 4 waves/SIMD instead of 3 (136 -> 408
// needs <=512; 4x136=544 > 512 was the occupancy cap at ~40%).
//  1. x1 fragments: afr[4] (16 VGPR, all chunks preloaded) -> rolling raw
//     float4-pair prefetch (8 VGPR): issue chunk ch+1's x1 loads during step
//     ch, convert to f16 at consumption. Same traffic, 1-step load->use.
//  2. ro1 removed: ((nI+8)^(kq<<1))*16 == (nI^(kq<<1))*16 + 128 always
//     (kq<<1 touches bits1-2 only; +8 flips bit3/carries to bit4), so
//     tile1 B-read = ro0 + 128 (folds into ds_read offset immediate).
// Everything else identical to round 3 (XCD swizzle, direct band stores,
// lgkm-only barriers, conflict-free swizzled staging).

namespace {
constexpr int Bb = 8, Hh = 128, Ww = 192, Cn = 128;
constexpr int MDc = 4;
constexpr int TH = 8, TWT = 16;        // block tile: 8 rows x 16 px
constexpr int NTHR = 512;              // 8 waves
constexpr int RH = 16;                 // staged warped rows  (h0-4 .. h0+11)
constexpr int RPX = 24;                // staged warped px    (w0-4 .. w0+19)
constexpr int KC = 32;                 // channels per chunk
constexpr int NCH = Cn / KC;           // 4
constexpr int KQB = RPX * 16;          // 384 B per kq-plane (24 x 16B slots)
constexpr int ROWB = 4 * KQB;          // 1536 B per staged row
constexpr int BUFB = RH * ROWB;        // 24576 B per buffer
constexpr int RUNS = RH * RPX * 4;     // 1536 8-channel runs per chunk
constexpr int NIT = RUNS / NTHR;       // 3
constexpr float NEG = 0.1f;
}

typedef __fp16 h2v   __attribute__((ext_vector_type(2)));
typedef __fp16 f16x8 __attribute__((ext_vector_type(8)));
typedef float  f32x4 __attribute__((ext_vector_type(4)));

__device__ __forceinline__ unsigned pkh2(float a, float b) {
    h2v h = __builtin_amdgcn_cvt_pkrtz(a, b);
    return __builtin_bit_cast(unsigned, h);
}

// Barrier with LDS-only drain: global prefetch loads stay in flight across it.
__device__ __forceinline__ void barrier_lgkm() {
    asm volatile("s_waitcnt lgkmcnt(0)\n\ts_barrier" ::: "memory");
}

__global__ __launch_bounds__(NTHR, 4)
void costvol_mfma(const float* __restrict__ x1,
                  const float* __restrict__ wp,
                  float* __restrict__ out)
{
    __shared__ __align__(16) unsigned char smem[2 * BUFB];   // 48 KiB

    const int tid  = threadIdx.x;
    const int wv   = tid >> 6;        // 0..7 : h-row within stripe
    const int lane = tid & 63;
    const int nI   = lane & 15;       // A-row m / B-col n lane index
    const int kq   = lane >> 4;       // 0..3 : k-group (8 channels each)

    // XCD swizzle: linear id round-robins across 8 XCDs; remap so XCD x gets
    // 192 consecutive wg = one full batch image (12 x 16 tiles).
    const int id = blockIdx.x;
    const int wg = (id & 7) * 192 + (id >> 3);
    const int bx = wg % 12;
    const int t2 = wg / 12;
    const int by = t2 & 15;
    const int bz = t2 >> 4;

    const int w0 = bx * TWT;
    const int h0 = by * TH;
    const int b  = bz;

    // ---- warped staging decode: run = (row, px, kq), kq innermost ----
    int g_off[NIT]; int l_off[NIT]; bool g_ok[NIT];
#pragma unroll
    for (int it = 0; it < NIT; ++it) {
        int s   = tid + it * NTHR;    // 0..1535
        int skq = s & 3;
        int t   = s >> 2;             // 0..383
        int px  = t % RPX;
        int row = t / RPX;
        int hw  = h0 - MDc + row;
        int ww  = w0 - MDc + px;
        bool ok = (unsigned)hw < (unsigned)Hh && (unsigned)ww < (unsigned)Ww;
        g_ok[it]  = ok;
        g_off[it] = ((b * Hh + (ok ? hw : 0)) * Ww + (ok ? ww : 0)) * Cn + skq * 8;
        l_off[it] = row * ROWB + skq * KQB + ((px ^ (skq << 1)) * 16);
    }

    uint4 gp[NIT];
    auto LOADCH = [&](int ch) {
#pragma unroll
        for (int it = 0; it < NIT; ++it) {
            if (g_ok[it]) {
                const float* p = wp + g_off[it] + ch * KC;
                float4 u = *reinterpret_cast<const float4*>(p);
                float4 v = *reinterpret_cast<const float4*>(p + 4);
                gp[it] = make_uint4(pkh2(u.x, u.y), pkh2(u.z, u.w),
                                    pkh2(v.x, v.y), pkh2(v.z, v.w));
            } else {
                gp[it] = make_uint4(0u, 0u, 0u, 0u);
            }
        }
    };
    auto WRITEB = [&](int buf) {
#pragma unroll
        for (int it = 0; it < NIT; ++it)
            *reinterpret_cast<uint4*>(smem + buf * BUFB + l_off[it]) = gp[it];
    };

    // issue first staging chunk before x1 loads (staging is the critical path)
    LOADCH(0);

    // ---- x1 rolling raw prefetch: 8 VGPRs hold next chunk's fp32 data ----
    const float* xp = x1 + ((size_t)((b * Hh + h0 + wv) * Ww) + w0 + nI) * Cn + kq * 8;
    float4 ar_u, ar_v;                 // raw x1 data for the upcoming chunk
    ar_u = *reinterpret_cast<const float4*>(xp);
    ar_v = *reinterpret_cast<const float4*>(xp + 4);

    f32x4 ac0[9], ac1[9];
#pragma unroll
    for (int s = 0; s < 9; ++s) {
        f32x4 z = {0.f, 0.f, 0.f, 0.f};
        ac0[s] = z; ac1[s] = z;
    }

    // per-lane B fragment offset within a staged row; tile1 = ro0 + 128
    const int ro0 = kq * KQB + ((nI ^ (kq << 1)) * 16);

    WRITEB(0); LOADCH(1);

    int cur = 0;
#pragma unroll
    for (int ch = 0; ch < NCH; ++ch) {
        barrier_lgkm();
        if (ch + 1 < NCH) WRITEB(cur ^ 1);
        if (ch + 2 < NCH) LOADCH(ch + 2);
        // convert this chunk's x1 (loaded last step), then issue next chunk
        uint4 afr = make_uint4(pkh2(ar_u.x, ar_u.y), pkh2(ar_u.z, ar_u.w),
                               pkh2(ar_v.x, ar_v.y), pkh2(ar_v.z, ar_v.w));
        if (ch + 1 < NCH) {
            ar_u = *reinterpret_cast<const float4*>(xp + (ch + 1) * KC);
            ar_v = *reinterpret_cast<const float4*>(xp + (ch + 1) * KC + 4);
        }
        f16x8 av = __builtin_bit_cast(f16x8, afr);
        const unsigned char* base = smem + cur * BUFB;
#pragma unroll
        for (int sh = 0; sh < 9; ++sh) {
            const unsigned char* rp = base + (wv + sh) * ROWB;   // staged row ly+sh
            uint4 b0 = *reinterpret_cast<const uint4*>(rp + ro0);
            uint4 b1 = *reinterpret_cast<const uint4*>(rp + ro0 + 128);
            ac0[sh] = __builtin_amdgcn_mfma_f32_16x16x32_f16(
                av, __builtin_bit_cast(f16x8, b0), ac0[sh], 0, 0, 0);
            ac1[sh] = __builtin_amdgcn_mfma_f32_16x16x32_f16(
                av, __builtin_bit_cast(f16x8, b1), ac1[sh], 0, 0, 0);
        }
        cur ^= 1;
    }

    // ---- direct band stores: no LDS round-trip, no barriers ----
    // C/D map: col=n=lane&15, row=m=(lane>>4)*4+reg
    // tile0: staged px p = nI      -> (m, sw4 = nI-m),   valid d=nI-m in [0,8]
    // tile1: staged px p = nI + 8  -> (m, sw4 = nI-m+8), valid d in [-8,0] && nI>=8
    // out k-index = sh*9 + sw4. Active lanes per (rg,sh,tile) write 4
    // contiguous 36B runs (one per kq) -> merged to full lines in L2.
    const float sc = 1.0f / (float)Cn;
    const size_t rowbase = ((size_t)((b * Hh + h0 + wv) * Ww) + w0) * 81;
#pragma unroll
    for (int rg = 0; rg < 4; ++rg) {
        int m = kq * 4 + rg;
        int d = nI - m;
        bool t0 = (d >= 0 && d <= 8);
        bool t1 = (d >= -8 && d <= 0 && nI >= 8);
        size_t mb = rowbase + (size_t)m * 81;
#pragma unroll
        for (int sh = 0; sh < 9; ++sh) {
            if (t0) {
                float v = ac0[sh][rg] * sc;
                v = (v >= 0.f) ? v : NEG * v;
                out[mb + sh * 9 + d] = v;
            }
            if (t1) {
                float v = ac1[sh][rg] * sc;
                v = (v >= 0.f) ? v : NEG * v;
                out[mb + sh * 9 + d + 8] = v;
            }
        }
    }
}

extern "C" void kernel_launch(void* const* d_in, const int* in_sizes, int n_in,
                              void* d_out, int out_size, void* d_ws, size_t ws_size,
                              hipStream_t stream) {
    const float* x1 = (const float*)d_in[0];
    const float* wp = (const float*)d_in[1];
    float* out = (float*)d_out;
    dim3 grid(12 * 16 * 8, 1, 1);   // 1536 blocks, XCD-swizzled in-kernel
    costvol_mfma<<<grid, NTHR, 0, stream>>>(x1, wp, out);
}